// Round 2
// baseline (78.909 us; speedup 1.0000x reference)
//
#include <hip/hip_runtime.h>
#include <math.h>

#define B 2
#define S 1024
#define H 1024
#define NIN 512
#define NP 32
#define SC 16            // s-chunks for ctx accumulation
#define SCHUNK (S / SC)  // 64

// ---------- K1: fused template-norm + pattern + nrm partials ----------
// grid = B*S/8 = 256 blocks; block 256 = 8 tokens x 32 templates
__global__ void k_pattern(const float* __restrict__ act, const float* __restrict__ tmpl,
                          float* __restrict__ P, float* __restrict__ nrm) {
    __shared__ float act_lds[8][NIN];   // 16 KB
    __shared__ float invn[NP];
    __shared__ float psum[8][NP];
    int tid = threadIdx.x;
    int t0 = blockIdx.x * 8;            // first token (global, b*S+s)
    int b  = t0 >> 10;

    // template inverse norms: 8 lanes per template
    {
        int n = tid >> 3, sub = tid & 7;
        const float* tr = tmpl + (size_t)n * NIN;
        float ss = 0.f;
#pragma unroll 16
        for (int k = 0; k < 64; ++k) { float x = tr[sub + 8 * k]; ss += x * x; }
        ss += __shfl_xor(ss, 1);
        ss += __shfl_xor(ss, 2);
        ss += __shfl_xor(ss, 4);
        if (sub == 0) invn[n] = 1.f / fmaxf(sqrtf(ss), 1e-12f);
    }
    // stage 8 act rows
    {
        const float* src = act + (size_t)t0 * NIN;
        float* dst = &act_lds[0][0];
        for (int k = tid; k < 8 * NIN; k += 256) dst[k] = src[k];
    }
    __syncthreads();

    int tok = tid >> 5;   // 0..7
    int n   = tid & 31;   // 0..31
    // act row sumsq (32 lanes of this token cooperate)
    float ss = 0.f;
#pragma unroll
    for (int k = 0; k < 16; ++k) { float x = act_lds[tok][n + 32 * k]; ss += x * x; }
#pragma unroll
    for (int m = 16; m; m >>= 1) ss += __shfl_xor(ss, m);
    float inva = 1.f / fmaxf(sqrtf(ss), 1e-12f);

    // dot(act_row, tmpl[n]) with raw template (scale by invn afterwards)
    const float4* t4 = (const float4*)(tmpl + (size_t)n * NIN);
    const float4* a4 = (const float4*)(&act_lds[tok][0]);
    float d = 0.f;
#pragma unroll 8
    for (int i = 0; i < NIN / 4; ++i) {
        float4 tv = t4[i];
        float4 av = a4[i];
        d += tv.x * av.x + tv.y * av.y + tv.z * av.z + tv.w * av.w;
    }
    d *= inva * invn[n];
    float p = 1.f / (1.f + expf(-d));
    P[(size_t)(t0 + tok) * NP + n] = p;

    // block-level partial column sums -> atomic into nrm[b,n]
    psum[tok][n] = p;
    __syncthreads();
    if (tid < NP) {
        float s = 0.f;
#pragma unroll
        for (int t = 0; t < 8; ++t) s += psum[t][tid];
        unsafeAtomicAdd(&nrm[b * NP + tid], s);
    }
}

// ---------- K2: ctx[b,n,h] += sum_s I[b,s,h]*P[b,s,n]  (unscaled, atomic) ----------
// grid = B * SC * 8 (h-tiles of 128) = 256 blocks; block 256 = 128 h x 2 n-groups of 16
__global__ void k_ctx(const float* __restrict__ I, const float* __restrict__ P,
                      float* __restrict__ ctx) {
    int bid = blockIdx.x;
    int ht = bid & 7;
    int sc = (bid >> 3) & (SC - 1);
    int b  = bid >> 7;
    int tid = threadIdx.x;
    __shared__ float Pl[SCHUNK][NP];   // 8 KB
    int s0 = sc * SCHUNK;
    {
        const float* src = P + ((size_t)b * S + s0) * NP;
        float* dst = &Pl[0][0];
        for (int k = tid; k < SCHUNK * NP; k += 256) dst[k] = src[k];
    }
    __syncthreads();
    int hl = tid & 127;
    int g  = tid >> 7;                 // 0/1 -> n in [16g, 16g+16)
    int h  = ht * 128 + hl;
    float acc[16];
#pragma unroll
    for (int j = 0; j < 16; ++j) acc[j] = 0.f;
    const float* Ip = I + ((size_t)b * S + s0) * H + h;
    for (int s = 0; s < SCHUNK; ++s) {
        float x = Ip[(size_t)s * H];
#pragma unroll
        for (int j = 0; j < 16; ++j) acc[j] += x * Pl[s][g * 16 + j];
    }
#pragma unroll
    for (int j = 0; j < 16; ++j)
        unsafeAtomicAdd(&ctx[((size_t)b * NP + g * 16 + j) * H + h], acc[j]);
}

// ---------- K3: T[b,n,k] = sum_h (ctx[b,n,h]/nrm[b,n]) * W[n,k,h] ----------
// grid = NP * 64 = 2048 blocks; block 256 = 4 waves, 4 rows per wave, no LDS
__global__ __launch_bounds__(256, 4)
void k_transform(const float* __restrict__ W, const float* __restrict__ ctx,
                 const float* __restrict__ nrm, float* __restrict__ T) {
    int bid = blockIdx.x;
    int n  = bid >> 6;     // 0..31
    int rg = bid & 63;     // row-group of 16
    int tid = threadIdx.x;
    int w = tid >> 6, lane = tid & 63;

    float inv0 = 1.f / (nrm[n] + 1e-8f);
    float inv1 = 1.f / (nrm[NP + n] + 1e-8f);

    // ctx fragment in registers: h = it*256 + lane*4 + {0..3}
    const float4* c0g = (const float4*)(ctx + (size_t)n * H);
    const float4* c1g = (const float4*)(ctx + ((size_t)NP + n) * H);
    float4 c0[4], c1[4];
#pragma unroll
    for (int it = 0; it < 4; ++it) {
        float4 v = c0g[it * 64 + lane];
        c0[it] = make_float4(v.x * inv0, v.y * inv0, v.z * inv0, v.w * inv0);
        float4 u = c1g[it * 64 + lane];
        c1[it] = make_float4(u.x * inv1, u.y * inv1, u.z * inv1, u.w * inv1);
    }

    int row0 = rg * 16 + w * 4;        // 4 rows for this wave
    const float4* Wr = (const float4*)(W + ((size_t)n * H + row0) * H);
    float a0[4] = {0.f, 0.f, 0.f, 0.f};
    float a1[4] = {0.f, 0.f, 0.f, 0.f};
#pragma unroll
    for (int it = 0; it < 4; ++it) {
#pragma unroll
        for (int r = 0; r < 4; ++r) {
            float4 wv = Wr[r * 256 + it * 64 + lane];
            a0[r] += wv.x * c0[it].x + wv.y * c0[it].y + wv.z * c0[it].z + wv.w * c0[it].w;
            a1[r] += wv.x * c1[it].x + wv.y * c1[it].y + wv.z * c1[it].z + wv.w * c1[it].w;
        }
    }
#pragma unroll
    for (int r = 0; r < 4; ++r) {
#pragma unroll
        for (int off = 32; off; off >>= 1) {
            a0[r] += __shfl_xor(a0[r], off);
            a1[r] += __shfl_xor(a1[r], off);
        }
    }
    if (lane == 0) {
#pragma unroll
        for (int r = 0; r < 4; ++r) {
            T[(size_t)n * H + row0 + r] = a0[r];
            T[((size_t)NP + n) * H + row0 + r] = a1[r];
        }
    }
}

// ---------- K4: combined[b,s,h] = sum_n T[b,n,h] * P[b,s,n] ----------
// grid = B * (S/16) * (H/256) = 512; block 256, thread owns one h
__global__ void k_combine(const float* __restrict__ T, const float* __restrict__ P,
                          float* __restrict__ out) {
    int bid = blockIdx.x;
    int ht = bid & 3;
    int sc = (bid >> 2) & 63;
    int b  = bid >> 8;
    int tid = threadIdx.x;
    __shared__ float Tl[NP][256];   // 32 KB
    __shared__ float Pl[16][NP];    // 2 KB
    int h0 = ht * 256;
    for (int k = tid; k < NP * 256; k += 256) {
        int n = k >> 8, h = k & 255;
        Tl[n][h] = T[((size_t)b * NP + n) * H + h0 + h];
    }
    int s0 = sc * 16;
    {
        const float* src = P + ((size_t)b * S + s0) * NP;
        float* dst = &Pl[0][0];
        for (int k = tid; k < 16 * NP; k += 256) dst[k] = src[k];
    }
    __syncthreads();
    for (int s = 0; s < 16; ++s) {
        float acc = 0.f;
#pragma unroll
        for (int n = 0; n < NP; ++n) acc += Pl[s][n] * Tl[n][tid];
        out[((size_t)b * S + s0 + s) * H + h0 + tid] = acc;
    }
}

extern "C" void kernel_launch(void* const* d_in, const int* in_sizes, int n_in,
                              void* d_out, int out_size, void* d_ws, size_t ws_size,
                              hipStream_t stream) {
    const float* I    = (const float*)d_in[0];  // [B,S,H]
    const float* act  = (const float*)d_in[1];  // [B,S,NIN]
    const float* tmpl = (const float*)d_in[2];  // [NP,NIN]
    const float* W    = (const float*)d_in[3];  // [NP*H,H]
    float* out  = (float*)d_out;                // combined [B,S,H]
    float* Pout = out + (size_t)B * S * H;      // process_activations [B,S,NP]

    float* ws  = (float*)d_ws;
    float* ctx = ws;                            // B*NP*H = 65536
    float* nrm = ctx + (size_t)B * NP * H;      // B*NP = 64
    float* T   = nrm + B * NP;                  // B*NP*H = 65536

    hipMemsetAsync(ctx, 0, (size_t)(B * NP * H + B * NP) * sizeof(float), stream);
    k_pattern  <<<B * S / 8,              256, 0, stream>>>(act, tmpl, Pout, nrm);
    k_ctx      <<<B * SC * 8,             256, 0, stream>>>(I, Pout, ctx);
    k_transform<<<NP * 64,                256, 0, stream>>>(W, ctx, nrm, T);
    k_combine  <<<B * (S/16) * (H/256),   256, 0, stream>>>(T, Pout, out);
}